// Round 5
// baseline (616.951 us; speedup 1.0000x reference)
//
#include <hip/hip_runtime.h>

typedef unsigned short ushort_t;
typedef unsigned short ushort8 __attribute__((ext_vector_type(8)));
typedef __bf16 bf16x8 __attribute__((ext_vector_type(8)));
typedef float f32x4 __attribute__((ext_vector_type(4)));

#define N_TOKENS 4096
#define D_MODEL  1024
#define D_HIDDEN 16384
#define TOPK     64
#define DELTA    0.03f   // >= 2*E, E = bf16-GEMM err (~5e-3) + bf16-Z quant (~4e-3)
#define RCAP     128     // max refine candidates per row (expect ~4)
#define T0SEL    1.25f   // candidate threshold; E[count]~248/row, v64~1.85 >> T0+DELTA
#define CAP      512     // candidate list capacity per row
#define CSL      16      // per-row staging slots per 128-col GEMM block (mean ~2)

__device__ __forceinline__ float bf2f(ushort_t u) {
  union { unsigned u; float f; } c; c.u = ((unsigned)u) << 16; return c.f;
}
__device__ __forceinline__ ushort_t f2bf(float f) {
  union { float f; unsigned u; } c; c.f = f;
  unsigned x = c.u;
  unsigned r = (x + 0x7FFFu + ((x >> 16) & 1u)) >> 16;  // RNE
  return (ushort_t)r;
}

typedef __attribute__((address_space(1))) void GV;
typedef __attribute__((address_space(3))) void LV;
__device__ __forceinline__ void llds16(const void* g, void* l) {
  __builtin_amdgcn_global_load_lds((GV*)g, (LV*)l, 16, 0, 0);
}

// ---------------------------------------------------------------------------
// Kernel 0: cast x fp32 -> bf16 ; also zeroes the per-row candidate counters
// (grid is exactly N_TOKENS blocks).
// ---------------------------------------------------------------------------
__global__ __launch_bounds__(256) void cast_x_kernel(
    const float* __restrict__ in, ushort_t* __restrict__ out,
    int* __restrict__ cnt) {
  if (threadIdx.x == 0) cnt[blockIdx.x] = 0;
  const int i = (blockIdx.x * 256 + threadIdx.x) * 4;
  float4 v = *(const float4*)&in[i];
  ushort4 o;
  o.x = f2bf(v.x); o.y = f2bf(v.y); o.z = f2bf(v.z); o.w = f2bf(v.w);
  *(ushort4*)&out[i] = o;
}

// ---------------------------------------------------------------------------
// Kernel 0b: cast W_dec fp32 [H][K] -> bf16 (into WT buffer after last GEMM)
// ---------------------------------------------------------------------------
__global__ __launch_bounds__(256) void cast_wdec_kernel(
    const float* __restrict__ in, ushort_t* __restrict__ out) {
  const int i = (blockIdx.x * 256 + threadIdx.x) * 8;
  float4 v0 = *(const float4*)&in[i];
  float4 v1 = *(const float4*)&in[i + 4];
  ushort8 o;
  o[0] = f2bf(v0.x); o[1] = f2bf(v0.y); o[2] = f2bf(v0.z); o[3] = f2bf(v0.w);
  o[4] = f2bf(v1.x); o[5] = f2bf(v1.y); o[6] = f2bf(v1.z); o[7] = f2bf(v1.w);
  *(ushort8*)&out[i] = o;
}

// ---------------------------------------------------------------------------
// Kernel 1: W_enc fp32 [D_MODEL][D_HIDDEN] -> bf16 WT [H][K] + fp32 WT32 [H][K]
// ---------------------------------------------------------------------------
__global__ __launch_bounds__(256) void transpose_cast_kernel(
    const float* __restrict__ in, ushort_t* __restrict__ outb,
    float* __restrict__ out32) {
  __shared__ float tile[64][68];
  const int tid = threadIdx.x;
  const int n0 = blockIdx.x * 64;
  const int k0 = blockIdx.y * 64;
#pragma unroll
  for (int i = 0; i < 4; ++i) {
    int e = i * 256 + tid;
    int kk = e >> 4;
    int nn = (e & 15) * 4;
    float4 v = *(const float4*)&in[(size_t)(k0 + kk) * D_HIDDEN + n0 + nn];
    tile[kk][nn + 0] = v.x;
    tile[kk][nn + 1] = v.y;
    tile[kk][nn + 2] = v.z;
    tile[kk][nn + 3] = v.w;
  }
  __syncthreads();
#pragma unroll
  for (int i = 0; i < 4; ++i) {
    int e = i * 256 + tid;
    int nn = e >> 4;
    int kk = (e & 15) * 4;
    float4 f;
    f.x = tile[kk + 0][nn];
    f.y = tile[kk + 1][nn];
    f.z = tile[kk + 2][nn];
    f.w = tile[kk + 3][nn];
    *(float4*)&out32[(size_t)(n0 + nn) * D_MODEL + k0 + kk] = f;
    ushort4 b;
    b.x = f2bf(f.x); b.y = f2bf(f.y); b.z = f2bf(f.z); b.w = f2bf(f.w);
    *(ushort4*)&outb[(size_t)(n0 + nn) * D_MODEL + k0 + kk] = b;
  }
}

// ---------------------------------------------------------------------------
// Kernel 2: Z~ = relu(x @ W_enc + b_enc), bf16 out.  m97-style 128x128xBK32.
// R11: candidate extraction folded into the epilogue the CHEAP way (vs R9):
//   - block-local LDS compaction reusing As/Bs (no extra LDS),
//   - per-row LDS counters (128 distinct addresses, no hot-spot),
//   - ONE global atomicAdd per (row, block) at distinct addresses,
//   - staged coalesced-ish copy-out (~2 entries/row avg).
// Z bf16 still written (fallback input). filter_kernel deleted.
// ---------------------------------------------------------------------------
__global__ __launch_bounds__(256) void encode_gemm(
    const ushort_t* __restrict__ X, const ushort_t* __restrict__ WT,
    const float* __restrict__ benc, ushort_t* __restrict__ Z,
    int* __restrict__ cnt, float* __restrict__ cvals, int* __restrict__ cidxs) {
  __shared__ ushort_t As[128 * 32];
  __shared__ ushort_t Bs[128 * 32];
  const int tid  = threadIdx.x;
  const int wave = tid >> 6, lane = tid & 63;
  const int m0 = blockIdx.y * 128;
  const int n0 = blockIdx.x * 128;
  const int wm = (wave >> 1) * 64;
  const int wn = (wave & 1) * 64;
  const int lr = lane >> 2;
  const int lk = (lane & 3) * 8;

  f32x4 acc[4][4];
#pragma unroll
  for (int i = 0; i < 4; ++i)
#pragma unroll
    for (int j = 0; j < 4; ++j) acc[i][j] = (f32x4){0.f, 0.f, 0.f, 0.f};

  for (int k0 = 0; k0 < D_MODEL; k0 += 32) {
    __syncthreads();
#pragma unroll
    for (int c = 0; c < 2; ++c) {
      const int chunk = c * 4 + wave;
      const int m = chunk * 16 + lr;
      llds16(&X [(size_t)(m0 + m) * D_MODEL + k0 + lk], &As[chunk * 512]);
      llds16(&WT[(size_t)(n0 + m) * D_MODEL + k0 + lk], &Bs[chunk * 512]);
    }
    __syncthreads();
    bf16x8 af[4], bfr[4];
#pragma unroll
    for (int t = 0; t < 4; ++t) {
      af[t]  = *(const bf16x8*)&As[(wm + t * 16 + (lane & 15)) * 32 + (lane >> 4) * 8];
      bfr[t] = *(const bf16x8*)&Bs[(wn + t * 16 + (lane & 15)) * 32 + (lane >> 4) * 8];
    }
#pragma unroll
    for (int mt = 0; mt < 4; ++mt)
#pragma unroll
      for (int nt = 0; nt < 4; ++nt)
        acc[mt][nt] = __builtin_amdgcn_mfma_f32_16x16x32_bf16(
            af[mt], bfr[nt], acc[mt][nt], 0, 0, 0);
  }

  // ---- epilogue with LDS candidate compaction (aliases As/Bs) ----
  float   (*svv)[CSL] = (float(*)[CSL])As;            // 128*16*4 = 8192 B
  ushort_t(*scc)[CSL] = (ushort_t(*)[CSL])Bs;         // 128*16*2 = 4096 B
  int*     lcnt       = (int*)&Bs[2048];              // 128*4    =  512 B
  __syncthreads();               // all waves done reading As/Bs
  if (tid < 128) lcnt[tid] = 0;
  __syncthreads();

  const int col_base = n0 + wn + (lane & 15);
  const int row_base = m0 + wm + (lane >> 4) * 4;
  const int lrow_base = wm + (lane >> 4) * 4;
#pragma unroll
  for (int nt = 0; nt < 4; ++nt) {
    const float bias = benc[col_base + nt * 16];
#pragma unroll
    for (int mt = 0; mt < 4; ++mt) {
#pragma unroll
      for (int r = 0; r < 4; ++r) {
        float v = fmaxf(acc[mt][nt][r] + bias, 0.0f);
        Z[(size_t)(row_base + mt * 16 + r) * D_HIDDEN + col_base + nt * 16] = f2bf(v);
        if (v > T0SEL) {
          const int lrw = lrow_base + mt * 16 + r;       // 0..127
          int p = atomicAdd(&lcnt[lrw], 1);
          if (p < CSL) {
            svv[lrw][p] = v;
            scc[lrw][p] = (ushort_t)(col_base + nt * 16);
          }
        }
      }
    }
  }
  __syncthreads();

  if (tid < 128) {
    const int lc   = lcnt[tid];
    const int grow = m0 + tid;
    if (lc > 0) {
      // overflow (>CSL staged) -> poison count so the row gets flagged
      const int add  = (lc <= CSL) ? lc : (CAP + 1);
      const int base = atomicAdd(&cnt[grow], add);
      if (lc <= CSL) {
        for (int i = 0; i < lc; ++i) {
          const int p = base + i;
          if (p < CAP) {
            cvals[(size_t)grow * CAP + p] = svv[tid][i];
            cidxs[(size_t)grow * CAP + p] = (int)scc[tid][i];
          }
        }
      }
    }
  }
}

// ---------------------------------------------------------------------------
// Kernel 3: exact top-64 from the candidate list (fp32 GEMM values, same
// semantics as the verified path: v64 by (value desc, idx asc), DELTA band,
// fp64 refine).  Good row iff 64 <= n <= CAP and v64 - DELTA > T0SEL;
// otherwise flag -> fallback redoes the row from Z.
// ---------------------------------------------------------------------------
__global__ __launch_bounds__(256) void topk_select_kernel(
    const int* __restrict__ cnt, const float* __restrict__ cvals,
    const int* __restrict__ cidxs, const float* __restrict__ x32,
    const float* __restrict__ WT32, const float* __restrict__ benc,
    float* __restrict__ vals, int* __restrict__ idxs, int* __restrict__ flags) {
  __shared__ float  sval[CAP];
  __shared__ int    sidx[CAP];
  __shared__ int    ridx[RCAP];
  __shared__ double rex[RCAP];
  __shared__ float  sV64;
  __shared__ int    selCount, refCount;
  const int tid = threadIdx.x;
  const int row = blockIdx.x;
  const int n = cnt[row];
  if (n < TOPK || n > CAP) { if (tid == 0) flags[row] = 1; return; }

  for (int j = tid; j < n; j += 256) {
    sval[j] = cvals[(size_t)row * CAP + j];
    sidx[j] = cidxs[(size_t)row * CAP + j];
  }
  if (tid == 0) { selCount = 0; refCount = 0; }
  __syncthreads();

  // exact 64th by (value desc, index asc); LDS reads are lockstep broadcasts
  for (int j = tid; j < n; j += 256) {
    float vj = sval[j]; int ij = sidx[j];
    int rank = 0;
    for (int j2 = 0; j2 < n; ++j2) {
      float v2 = sval[j2];
      rank += (v2 > vj) || (v2 == vj && sidx[j2] < ij);
    }
    if (rank == TOPK - 1) sV64 = vj;
  }
  __syncthreads();
  const float v64 = sV64;
  if (v64 <= T0SEL + DELTA) { if (tid == 0) flags[row] = 1; return; }

  // classify: sure-selects vs refine band
  for (int j = tid; j < n; j += 256) {
    float v = sval[j];
    if (v > v64 + DELTA) {
      int p = atomicAdd(&selCount, 1);
      vals[(size_t)row * TOPK + p] = v;
      idxs[(size_t)row * TOPK + p] = sidx[j];
    } else if (v >= v64 - DELTA) {
      int c = atomicAdd(&refCount, 1);
      if (c < RCAP) ridx[c] = sidx[j];
    }
  }
  __syncthreads();
  if (refCount > RCAP) { if (tid == 0) flags[row] = 1; return; }
  if (tid == 0) flags[row] = 0;
  const int nS = selCount;
  const int nR = refCount;
  const int rNeed = TOPK - nS;

  // Phase D: exact fp64 dots, one wave per candidate (lane covers 16 cols)
  const int wave = tid >> 6, lane = tid & 63;
  float xr[16];
  {
    const float* xrb = &x32[(size_t)row * D_MODEL + lane * 16];
#pragma unroll
    for (int q = 0; q < 4; ++q)
      *(float4*)&xr[q * 4] = *(const float4*)&xrb[q * 4];
  }
  for (int c = wave; c < nR; c += 4) {
    const int j = ridx[c];
    const float* wr = &WT32[(size_t)j * D_MODEL];
    double p0 = 0.0, p1 = 0.0;
#pragma unroll
    for (int q = 0; q < 2; ++q) {
      const float4 wa = *(const float4*)&wr[lane * 16 + q * 8];
      const float4 wb = *(const float4*)&wr[lane * 16 + q * 8 + 4];
      p0 += (double)xr[q * 8 + 0] * wa.x + (double)xr[q * 8 + 1] * wa.y
          + (double)xr[q * 8 + 2] * wa.z + (double)xr[q * 8 + 3] * wa.w;
      p1 += (double)xr[q * 8 + 4] * wb.x + (double)xr[q * 8 + 5] * wb.y
          + (double)xr[q * 8 + 6] * wb.z + (double)xr[q * 8 + 7] * wb.w;
    }
    double part = p0 + p1;
#pragma unroll
    for (int off = 32; off > 0; off >>= 1) part += __shfl_down(part, off, 64);
    if (lane == 0) {
      double d = part + (double)benc[j];
      rex[c] = d > 0.0 ? d : 0.0;
    }
  }
  __syncthreads();

  // Phase E: rank refined by (value desc, index asc), take top rNeed
  for (int c = tid; c < nR; c += 256) {
    double vc = rex[c]; int ic = ridx[c];
    int rank = 0;
    for (int c2 = 0; c2 < nR; ++c2) {
      double v2 = rex[c2];
      rank += (v2 > vc) || (v2 == vc && ridx[c2] < ic);
    }
    if (rank < rNeed) {
      int p = atomicAdd(&selCount, 1);
      vals[(size_t)row * TOPK + p] = (float)vc;
      idxs[(size_t)row * TOPK + p] = ic;
    }
  }
}

// ---------------------------------------------------------------------------
// Kernel 3b: fallback — full-row top-64 from bf16 Z (verbatim verified path),
// runs only for flagged rows (statistically never; correctness insurance).
// ---------------------------------------------------------------------------
__global__ __launch_bounds__(256) void topk_fallback_kernel(
    const int* __restrict__ flags,
    const ushort_t* __restrict__ Z, const float* __restrict__ x32,
    const float* __restrict__ WT32, const float* __restrict__ benc,
    float* __restrict__ vals, int* __restrict__ idxs) {
  if (flags[blockIdx.x] == 0) return;
  __shared__ int hist[512 * 9 + 32];
  float*  cval = (float*)hist;                 // [512]
  int*    cidx = (int*)hist + 512;             // [512]
  int*    ridx = (int*)hist + 1024;            // [RCAP]
  double* rex  = (double*)((int*)hist + 1156); // [RCAP]
  __shared__ int   wtot[4];
  __shared__ int   sTbin, sAbove, selCount, candCount, refCount;
  __shared__ float sV64;

  const int tid  = threadIdx.x;
  const int wave = tid >> 6, lane = tid & 63;
  const int row  = blockIdx.x;
  const ushort_t* zr = Z + (size_t)row * D_HIDDEN;

  ushort8 u8v[8];
#pragma unroll
  for (int i = 0; i < 8; ++i) u8v[i] = *(const ushort8*)&zr[i * 2048 + tid * 8];
#define ZIDX(i, j) ((i) * 2048 + tid * 8 + (j))

  for (int k = tid; k < 512 * 9; k += 256) hist[k] = 0;
  if (tid == 0) { sTbin = -1; selCount = 0; candCount = 0; refCount = 0; }
  __syncthreads();

  const int cpy = lane & 7;
#pragma unroll
  for (int i = 0; i < 8; ++i)
#pragma unroll
    for (int j = 0; j < 8; ++j) {
      ushort_t w = u8v[i][j];
      if (w) atomicAdd(&hist[((int)(w >> 6)) * 9 + cpy], 1);
    }
  __syncthreads();

  int h0 = 0, h1 = 0;
#pragma unroll
  for (int c = 0; c < 8; ++c) {
    int cc = (tid + c) & 7;
    h0 += hist[(2 * tid) * 9 + cc];
    h1 += hist[(2 * tid + 1) * 9 + cc];
  }
  const int s = h0 + h1;
  int x = s;
#pragma unroll
  for (int off = 1; off < 64; off <<= 1) {
    int y = __shfl_down(x, off, 64);
    if (lane + off < 64) x += y;
  }
  if (lane == 0) wtot[wave] = x;
  __syncthreads();
  int cross = 0;
  if (wave < 3) cross += wtot[3];
  if (wave < 2) cross += wtot[2];
  if (wave < 1) cross += wtot[1];
  const int Sexc = cross + x - s;
  if (Sexc < TOPK && Sexc + h1 >= TOPK) { sTbin = 2 * tid + 1; sAbove = Sexc; }
  const int c0 = Sexc + h1;
  if (c0 < TOPK && c0 + h0 >= TOPK) { sTbin = 2 * tid; sAbove = c0; }
  __syncthreads();
  const int Tbin = sTbin, nAbove = sAbove;

  if (Tbin < 0) {
#pragma unroll
    for (int i = 0; i < 8; ++i)
#pragma unroll
      for (int j = 0; j < 8; ++j) {
        ushort_t w = u8v[i][j];
        if (w) {
          int p = atomicAdd(&selCount, 1);
          if (p < TOPK) { vals[row * 64 + p] = bf2f(w); idxs[row * 64 + p] = ZIDX(i, j); }
        }
      }
    __syncthreads();
    for (int p2 = min(selCount, TOPK) + tid; p2 < TOPK; p2 += 256) {
      vals[row * 64 + p2] = 0.0f; idxs[row * 64 + p2] = 0;
    }
    return;
  }

#pragma unroll
  for (int i = 0; i < 8; ++i)
#pragma unroll
    for (int j = 0; j < 8; ++j) {
      ushort_t w = u8v[i][j];
      if (w && (int)(w >> 6) == Tbin) {
        int c = atomicAdd(&candCount, 1);
        if (c < 512) { cval[c] = bf2f(w); cidx[c] = ZIDX(i, j); }
      }
    }
  __syncthreads();
  {
    const int r  = TOPK - nAbove;
    const int nc = min(candCount, 512);
    for (int j = tid; j < nc; j += 256) {
      float vj = cval[j]; int ij = cidx[j];
      int rank = 0;
      for (int j2 = 0; j2 < nc; ++j2) {
        float v2 = cval[j2];
        rank += (v2 > vj) || (v2 == vj && cidx[j2] < ij);
      }
      if (rank == r - 1) sV64 = vj;
    }
  }
  __syncthreads();
  const float v64 = sV64;

#pragma unroll
  for (int i = 0; i < 8; ++i)
#pragma unroll
    for (int j = 0; j < 8; ++j) {
      ushort_t w = u8v[i][j];
      if (!w) continue;
      float v = bf2f(w);
      if (v > v64 + DELTA) {
        int p = atomicAdd(&selCount, 1);
        vals[row * 64 + p] = v;
        idxs[row * 64 + p] = ZIDX(i, j);
      } else if (v >= v64 - DELTA) {
        int c = atomicAdd(&refCount, 1);
        if (c < RCAP) ridx[c] = ZIDX(i, j);
      }
    }
  __syncthreads();
  const int nS = selCount;
  const int nR = min(refCount, RCAP);
  const int rNeed = TOPK - nS;

  float xr[16];
  {
    const float* xrb = &x32[(size_t)row * D_MODEL + lane * 16];
#pragma unroll
    for (int q = 0; q < 4; ++q)
      *(float4*)&xr[q * 4] = *(const float4*)&xrb[q * 4];
  }
  for (int c = wave; c < nR; c += 4) {
    const int j = ridx[c];
    const float* wr = &WT32[(size_t)j * D_MODEL];
    double p0 = 0.0, p1 = 0.0;
#pragma unroll
    for (int q = 0; q < 2; ++q) {
      const float4 wa = *(const float4*)&wr[lane * 16 + q * 8];
      const float4 wb = *(const float4*)&wr[lane * 16 + q * 8 + 4];
      p0 += (double)xr[q * 8 + 0] * wa.x + (double)xr[q * 8 + 1] * wa.y
          + (double)xr[q * 8 + 2] * wa.z + (double)xr[q * 8 + 3] * wa.w;
      p1 += (double)xr[q * 8 + 4] * wb.x + (double)xr[q * 8 + 5] * wb.y
          + (double)xr[q * 8 + 6] * wb.z + (double)xr[q * 8 + 7] * wb.w;
    }
    double part = p0 + p1;
#pragma unroll
    for (int off = 32; off > 0; off >>= 1) part += __shfl_down(part, off, 64);
    if (lane == 0) {
      double d = part + (double)benc[j];
      rex[c] = d > 0.0 ? d : 0.0;
    }
  }
  __syncthreads();

  for (int c = tid; c < nR; c += 256) {
    double vc = rex[c]; int ic = ridx[c];
    int rank = 0;
    for (int c2 = 0; c2 < nR; ++c2) {
      double v2 = rex[c2];
      rank += (v2 > vc) || (v2 == vc && ridx[c2] < ic);
    }
    if (rank < rNeed) {
      int p = atomicAdd(&selCount, 1);
      vals[row * 64 + p] = (float)vc;
      idxs[row * 64 + p] = ic;
    }
  }
}

// ---------------------------------------------------------------------------
// Kernel 4: y = b_dec + sum_j vals[j]*W_dec[idx[j],:]  (bf16 gathers, fp32 out)
// ---------------------------------------------------------------------------
__global__ __launch_bounds__(256) void decode_kernel(
    const float* __restrict__ vals, const int* __restrict__ idxs,
    const ushort_t* __restrict__ Wdec_bf, const float* __restrict__ bdec,
    float* __restrict__ Y) {
  __shared__ float sv[2][TOPK];
  __shared__ int   si[2][TOPK];
  const int tid = threadIdx.x;
  const int r0  = blockIdx.x * 2;
  if (tid < 128) {
    int rr = tid >> 6, jj = tid & 63;
    sv[rr][jj] = vals[(r0 + rr) * 64 + jj];
    si[rr][jj] = idxs[(r0 + rr) * 64 + jj];
  }
  __syncthreads();
  const int rr  = tid >> 7;
  const int c0  = (tid & 127) * 8;
  const int row = r0 + rr;
  float4 b0 = *(const float4*)&bdec[c0];
  float4 b1 = *(const float4*)&bdec[c0 + 4];
  float a[8] = {b0.x, b0.y, b0.z, b0.w, b1.x, b1.y, b1.z, b1.w};
#pragma unroll 8
  for (int j = 0; j < TOPK; ++j) {
    const float vj = sv[rr][j];
    ushort8 w = *(const ushort8*)&Wdec_bf[(size_t)si[rr][j] * D_MODEL + c0];
#pragma unroll
    for (int u = 0; u < 8; ++u) a[u] += vj * bf2f(w[u]);
  }
  *(float4*)&Y[(size_t)row * D_MODEL + c0]     = (float4){a[0], a[1], a[2], a[3]};
  *(float4*)&Y[(size_t)row * D_MODEL + c0 + 4] = (float4){a[4], a[5], a[6], a[7]};
}

// ---------------------------------------------------------------------------
extern "C" void kernel_launch(void* const* d_in, const int* in_sizes, int n_in,
                              void* d_out, int out_size, void* d_ws, size_t ws_size,
                              hipStream_t stream) {
  const float* x     = (const float*)d_in[0];
  const float* W_enc = (const float*)d_in[1];
  const float* b_enc = (const float*)d_in[2];
  const float* W_dec = (const float*)d_in[3];
  const float* b_dec = (const float*)d_in[4];

  const size_t WT_BYTES   = (size_t)D_HIDDEN * D_MODEL * sizeof(ushort_t); // 32 MB
  const size_t WT32_BYTES = (size_t)D_HIDDEN * D_MODEL * sizeof(float);    // 64 MB
  const size_t XB_BYTES   = (size_t)N_TOKENS * D_MODEL * sizeof(ushort_t); //  8 MB
  const size_t V_BYTES    = (size_t)N_TOKENS * TOPK * sizeof(float);       //  1 MB
  const size_t CNT_BYTES  = (size_t)N_TOKENS * sizeof(int);                // 16 KB
  const size_t CV_BYTES   = (size_t)N_TOKENS * CAP * sizeof(float);        //  8 MB
  const size_t FIXED      = WT_BYTES + WT32_BYTES + XB_BYTES + 2 * V_BYTES
                          + 2 * CNT_BYTES + 2 * CV_BYTES;                  // ~122 MB

  int chunk_rows = 4096;  // bf16 Z chunk: 128 MB -> total ~250 MB; auto-shrink
  while (chunk_rows > 128 &&
         FIXED + (size_t)chunk_rows * D_HIDDEN * sizeof(ushort_t) > ws_size)
    chunk_rows >>= 1;

  char* ws = (char*)d_ws;
  size_t off = 0;
  ushort_t* WT    = (ushort_t*)(ws + off); off += WT_BYTES;
  float*    WT32  = (float*)(ws + off);    off += WT32_BYTES;
  ushort_t* XB    = (ushort_t*)(ws + off); off += XB_BYTES;
  float*    vals  = (float*)(ws + off);    off += V_BYTES;
  int*      idxs  = (int*)(ws + off);      off += V_BYTES;
  int*      cnt   = (int*)(ws + off);      off += CNT_BYTES;
  int*      flags = (int*)(ws + off);      off += CNT_BYTES;
  float*    cvals = (float*)(ws + off);    off += CV_BYTES;
  int*      cidxs = (int*)(ws + off);      off += CV_BYTES;
  ushort_t* Z     = (ushort_t*)(ws + off);
  float*    Y     = (float*)d_out;

  cast_x_kernel<<<dim3(N_TOKENS * D_MODEL / 1024), 256, 0, stream>>>(x, XB, cnt);
  transpose_cast_kernel<<<dim3(D_HIDDEN / 64, D_MODEL / 64), 256, 0, stream>>>(
      W_enc, WT, WT32);

  for (int r0 = 0; r0 < N_TOKENS; r0 += chunk_rows) {
    encode_gemm<<<dim3(D_HIDDEN / 128, chunk_rows / 128), 256, 0, stream>>>(
        XB + (size_t)r0 * D_MODEL, WT, b_enc, Z,
        cnt + r0, cvals + (size_t)r0 * CAP, cidxs + (size_t)r0 * CAP);
    topk_select_kernel<<<dim3(chunk_rows), 256, 0, stream>>>(
        cnt + r0, cvals + (size_t)r0 * CAP, cidxs + (size_t)r0 * CAP,
        x + (size_t)r0 * D_MODEL, WT32, b_enc,
        vals + (size_t)r0 * TOPK, idxs + (size_t)r0 * TOPK, flags + r0);
    topk_fallback_kernel<<<dim3(chunk_rows), 256, 0, stream>>>(
        flags + r0, Z, x + (size_t)r0 * D_MODEL, WT32, b_enc,
        vals + (size_t)r0 * TOPK, idxs + (size_t)r0 * TOPK);
  }

  cast_wdec_kernel<<<dim3(D_HIDDEN * D_MODEL / (256 * 8)), 256, 0, stream>>>(W_dec, WT);

  decode_kernel<<<dim3(N_TOKENS / 2), 256, 0, stream>>>(vals, idxs, WT, b_dec, Y);
}

// Round 6
// 529.344 us; speedup vs baseline: 1.1655x; 1.1655x over previous
//
#include <hip/hip_runtime.h>

typedef unsigned short ushort_t;
typedef unsigned short ushort8 __attribute__((ext_vector_type(8)));
typedef __bf16 bf16x8 __attribute__((ext_vector_type(8)));
typedef float f32x4 __attribute__((ext_vector_type(4)));

#define N_TOKENS 4096
#define D_MODEL  1024
#define D_HIDDEN 16384
#define TOPK     64
#define DELTA    0.03f   // >= 2*E, E = bf16-GEMM err (~5e-3) + bf16-Z quant (~4e-3)
#define RCAP     128     // max refine candidates per row (expect ~4)
#define T0SEL    1.25f   // candidate threshold; E[count]~249/row, v64~1.85 >> T0+DELTA
#define CAP      512     // candidate list capacity per row (E=249, sd~15)

__device__ __forceinline__ float bf2f(ushort_t u) {
  union { unsigned u; float f; } c; c.u = ((unsigned)u) << 16; return c.f;
}
__device__ __forceinline__ ushort_t f2bf(float f) {
  union { float f; unsigned u; } c; c.f = f;
  unsigned x = c.u;
  unsigned r = (x + 0x7FFFu + ((x >> 16) & 1u)) >> 16;  // RNE
  return (ushort_t)r;
}

typedef __attribute__((address_space(1))) void GV;
typedef __attribute__((address_space(3))) void LV;
__device__ __forceinline__ void llds16(const void* g, void* l) {
  __builtin_amdgcn_global_load_lds((GV*)g, (LV*)l, 16, 0, 0);
}

// ---------------------------------------------------------------------------
// Kernel 0: cast x fp32 -> bf16
// ---------------------------------------------------------------------------
__global__ __launch_bounds__(256) void cast_x_kernel(
    const float* __restrict__ in, ushort_t* __restrict__ out) {
  const int i = (blockIdx.x * 256 + threadIdx.x) * 4;
  float4 v = *(const float4*)&in[i];
  ushort4 o;
  o.x = f2bf(v.x); o.y = f2bf(v.y); o.z = f2bf(v.z); o.w = f2bf(v.w);
  *(ushort4*)&out[i] = o;
}

// ---------------------------------------------------------------------------
// Kernel 0b: cast W_dec fp32 [H][K] -> bf16 (into WT buffer after last GEMM)
// ---------------------------------------------------------------------------
__global__ __launch_bounds__(256) void cast_wdec_kernel(
    const float* __restrict__ in, ushort_t* __restrict__ out) {
  const int i = (blockIdx.x * 256 + threadIdx.x) * 8;
  float4 v0 = *(const float4*)&in[i];
  float4 v1 = *(const float4*)&in[i + 4];
  ushort8 o;
  o[0] = f2bf(v0.x); o[1] = f2bf(v0.y); o[2] = f2bf(v0.z); o[3] = f2bf(v0.w);
  o[4] = f2bf(v1.x); o[5] = f2bf(v1.y); o[6] = f2bf(v1.z); o[7] = f2bf(v1.w);
  *(ushort8*)&out[i] = o;
}

// ---------------------------------------------------------------------------
// Kernel 1: W_enc fp32 [D_MODEL][D_HIDDEN] -> bf16 WT [H][K] + fp32 WT32 [H][K]
// ---------------------------------------------------------------------------
__global__ __launch_bounds__(256) void transpose_cast_kernel(
    const float* __restrict__ in, ushort_t* __restrict__ outb,
    float* __restrict__ out32) {
  __shared__ float tile[64][68];
  const int tid = threadIdx.x;
  const int n0 = blockIdx.x * 64;
  const int k0 = blockIdx.y * 64;
#pragma unroll
  for (int i = 0; i < 4; ++i) {
    int e = i * 256 + tid;
    int kk = e >> 4;
    int nn = (e & 15) * 4;
    float4 v = *(const float4*)&in[(size_t)(k0 + kk) * D_HIDDEN + n0 + nn];
    tile[kk][nn + 0] = v.x;
    tile[kk][nn + 1] = v.y;
    tile[kk][nn + 2] = v.z;
    tile[kk][nn + 3] = v.w;
  }
  __syncthreads();
#pragma unroll
  for (int i = 0; i < 4; ++i) {
    int e = i * 256 + tid;
    int nn = e >> 4;
    int kk = (e & 15) * 4;
    float4 f;
    f.x = tile[kk + 0][nn];
    f.y = tile[kk + 1][nn];
    f.z = tile[kk + 2][nn];
    f.w = tile[kk + 3][nn];
    *(float4*)&out32[(size_t)(n0 + nn) * D_MODEL + k0 + kk] = f;
    ushort4 b;
    b.x = f2bf(f.x); b.y = f2bf(f.y); b.z = f2bf(f.z); b.w = f2bf(f.w);
    *(ushort4*)&outb[(size_t)(n0 + nn) * D_MODEL + k0 + kk] = b;
  }
}

// ---------------------------------------------------------------------------
// Kernel 2: Z~ = relu(x @ W_enc + b_enc), bf16 out.  m97-style 128x128xBK32.
// R12: byte-identical to the verified R0/R10 form (183 us, MfmaUtil ~33%).
// NO side-channel in the epilogue — R9/R11 both proved any fine-grained
// global write here costs 46-350 us.
// ---------------------------------------------------------------------------
__global__ __launch_bounds__(256) void encode_gemm(
    const ushort_t* __restrict__ X, const ushort_t* __restrict__ WT,
    const float* __restrict__ benc, ushort_t* __restrict__ Z) {
  __shared__ ushort_t As[128 * 32];
  __shared__ ushort_t Bs[128 * 32];
  const int tid  = threadIdx.x;
  const int wave = tid >> 6, lane = tid & 63;
  const int m0 = blockIdx.y * 128;
  const int n0 = blockIdx.x * 128;
  const int wm = (wave >> 1) * 64;
  const int wn = (wave & 1) * 64;
  const int lr = lane >> 2;
  const int lk = (lane & 3) * 8;

  f32x4 acc[4][4];
#pragma unroll
  for (int i = 0; i < 4; ++i)
#pragma unroll
    for (int j = 0; j < 4; ++j) acc[i][j] = (f32x4){0.f, 0.f, 0.f, 0.f};

  for (int k0 = 0; k0 < D_MODEL; k0 += 32) {
    __syncthreads();
#pragma unroll
    for (int c = 0; c < 2; ++c) {
      const int chunk = c * 4 + wave;
      const int m = chunk * 16 + lr;
      llds16(&X [(size_t)(m0 + m) * D_MODEL + k0 + lk], &As[chunk * 512]);
      llds16(&WT[(size_t)(n0 + m) * D_MODEL + k0 + lk], &Bs[chunk * 512]);
    }
    __syncthreads();
    bf16x8 af[4], bfr[4];
#pragma unroll
    for (int t = 0; t < 4; ++t) {
      af[t]  = *(const bf16x8*)&As[(wm + t * 16 + (lane & 15)) * 32 + (lane >> 4) * 8];
      bfr[t] = *(const bf16x8*)&Bs[(wn + t * 16 + (lane & 15)) * 32 + (lane >> 4) * 8];
    }
#pragma unroll
    for (int mt = 0; mt < 4; ++mt)
#pragma unroll
      for (int nt = 0; nt < 4; ++nt)
        acc[mt][nt] = __builtin_amdgcn_mfma_f32_16x16x32_bf16(
            af[mt], bfr[nt], acc[mt][nt], 0, 0, 0);
  }

  const int col_base = n0 + wn + (lane & 15);
  const int row_base = m0 + wm + (lane >> 4) * 4;
#pragma unroll
  for (int nt = 0; nt < 4; ++nt) {
    const float bias = benc[col_base + nt * 16];
#pragma unroll
    for (int mt = 0; mt < 4; ++mt) {
#pragma unroll
      for (int r = 0; r < 4; ++r) {
        float v = fmaxf(acc[mt][nt][r] + bias, 0.0f);
        Z[(size_t)(row_base + mt * 16 + r) * D_HIDDEN + col_base + nt * 16] = f2bf(v);
      }
    }
  }
}

// ---------------------------------------------------------------------------
// Kernel 3 (R12): FUSED filter + select. One block per row.
//  - coalesced Z-row read (32 KB/block), ballot/popc wave compaction into LDS
//    (1 LDS atomic per wave per 8 values, no per-value atomics),
//  - then the verified select semantics on the LDS list: exact v64 by
//    (value desc, index asc), DELTA band, fp64 refine via WT32.
// Kills the cvals/cidxs/cnt global round-trip and two kernel launches.
// Bails (flag=1) to the Z-based fallback on n<64, n>CAP, or v64 too close
// to T0SEL (statistically never).
// ---------------------------------------------------------------------------
__global__ __launch_bounds__(256) void topk_fused_kernel(
    const ushort_t* __restrict__ Z, const float* __restrict__ x32,
    const float* __restrict__ WT32, const float* __restrict__ benc,
    float* __restrict__ vals, int* __restrict__ idxs, int* __restrict__ flags) {
  __shared__ float  sval[CAP];
  __shared__ int    sidx[CAP];
  __shared__ int    ridx[RCAP];
  __shared__ double rex[RCAP];
  __shared__ float  sV64;
  __shared__ int    lcnt, selCount, refCount;
  const int tid  = threadIdx.x;
  const int lane = tid & 63;
  const int row  = blockIdx.x;
  const ushort_t* zr = Z + (size_t)row * D_HIDDEN;

  // preload the row slice (8 x ushort8 = 32 VGPRs), issue all loads up front
  ushort8 u8v[8];
#pragma unroll
  for (int i = 0; i < 8; ++i) u8v[i] = *(const ushort8*)&zr[i * 2048 + tid * 8];

  if (tid == 0) { lcnt = 0; selCount = 0; refCount = 0; }
  __syncthreads();

  // ---- filter via ballot compaction ----
#pragma unroll
  for (int i = 0; i < 8; ++i) {
#pragma unroll
    for (int j = 0; j < 8; ++j) {
      const float f = bf2f(u8v[i][j]);
      const bool sel = f > T0SEL;
      const unsigned long long mask = __ballot(sel);
      if (mask) {
        int base = 0;
        if (lane == 0) base = atomicAdd(&lcnt, __popcll(mask));
        base = __shfl(base, 0, 64);
        if (sel) {
          const int p = base + __popcll(mask & ((1ull << lane) - 1ull));
          if (p < CAP) {
            sval[p] = f;
            sidx[p] = i * 2048 + tid * 8 + j;
          }
        }
      }
    }
  }
  __syncthreads();
  const int n = lcnt;
  if (n < TOPK || n > CAP) { if (tid == 0) flags[row] = 1; return; }

  // ---- exact 64th by (value desc, index asc); LDS reads are broadcasts ----
  for (int j = tid; j < n; j += 256) {
    float vj = sval[j]; int ij = sidx[j];
    int rank = 0;
    for (int j2 = 0; j2 < n; ++j2) {
      float v2 = sval[j2];
      rank += (v2 > vj) || (v2 == vj && sidx[j2] < ij);
    }
    if (rank == TOPK - 1) sV64 = vj;
  }
  __syncthreads();
  const float v64 = sV64;
  if (v64 <= T0SEL + DELTA) { if (tid == 0) flags[row] = 1; return; }

  // ---- classify: sure-selects vs refine band ----
  for (int j = tid; j < n; j += 256) {
    float v = sval[j];
    if (v > v64 + DELTA) {
      int p = atomicAdd(&selCount, 1);
      vals[(size_t)row * TOPK + p] = v;
      idxs[(size_t)row * TOPK + p] = sidx[j];
    } else if (v >= v64 - DELTA) {
      int c = atomicAdd(&refCount, 1);
      if (c < RCAP) ridx[c] = sidx[j];
    }
  }
  __syncthreads();
  if (refCount > RCAP) { if (tid == 0) flags[row] = 1; return; }
  if (tid == 0) flags[row] = 0;
  const int nS = selCount;
  const int nR = refCount;
  const int rNeed = TOPK - nS;

  // ---- Phase D: exact fp64 dots, one wave per candidate ----
  const int wave = tid >> 6;
  float xr[16];
  {
    const float* xrb = &x32[(size_t)row * D_MODEL + lane * 16];
#pragma unroll
    for (int q = 0; q < 4; ++q)
      *(float4*)&xr[q * 4] = *(const float4*)&xrb[q * 4];
  }
  for (int c = wave; c < nR; c += 4) {
    const int j = ridx[c];
    const float* wr = &WT32[(size_t)j * D_MODEL];
    double p0 = 0.0, p1 = 0.0;
#pragma unroll
    for (int q = 0; q < 2; ++q) {
      const float4 wa = *(const float4*)&wr[lane * 16 + q * 8];
      const float4 wb = *(const float4*)&wr[lane * 16 + q * 8 + 4];
      p0 += (double)xr[q * 8 + 0] * wa.x + (double)xr[q * 8 + 1] * wa.y
          + (double)xr[q * 8 + 2] * wa.z + (double)xr[q * 8 + 3] * wa.w;
      p1 += (double)xr[q * 8 + 4] * wb.x + (double)xr[q * 8 + 5] * wb.y
          + (double)xr[q * 8 + 6] * wb.z + (double)xr[q * 8 + 7] * wb.w;
    }
    double part = p0 + p1;
#pragma unroll
    for (int off = 32; off > 0; off >>= 1) part += __shfl_down(part, off, 64);
    if (lane == 0) {
      double d = part + (double)benc[j];
      rex[c] = d > 0.0 ? d : 0.0;
    }
  }
  __syncthreads();

  // ---- Phase E: rank refined by (value desc, index asc), take top rNeed ----
  for (int c = tid; c < nR; c += 256) {
    double vc = rex[c]; int ic = ridx[c];
    int rank = 0;
    for (int c2 = 0; c2 < nR; ++c2) {
      double v2 = rex[c2];
      rank += (v2 > vc) || (v2 == vc && ridx[c2] < ic);
    }
    if (rank < rNeed) {
      int p = atomicAdd(&selCount, 1);
      vals[(size_t)row * TOPK + p] = (float)vc;
      idxs[(size_t)row * TOPK + p] = ic;
    }
  }
}

// ---------------------------------------------------------------------------
// Kernel 3b: fallback — full-row top-64 from bf16 Z (verbatim verified path),
// runs only for flagged rows (statistically never; correctness insurance).
// ---------------------------------------------------------------------------
__global__ __launch_bounds__(256) void topk_fallback_kernel(
    const int* __restrict__ flags,
    const ushort_t* __restrict__ Z, const float* __restrict__ x32,
    const float* __restrict__ WT32, const float* __restrict__ benc,
    float* __restrict__ vals, int* __restrict__ idxs) {
  if (flags[blockIdx.x] == 0) return;
  __shared__ int hist[512 * 9 + 32];
  float*  cval = (float*)hist;                 // [512]
  int*    cidx = (int*)hist + 512;             // [512]
  int*    ridx = (int*)hist + 1024;            // [RCAP]
  double* rex  = (double*)((int*)hist + 1156); // [RCAP]
  __shared__ int   wtot[4];
  __shared__ int   sTbin, sAbove, selCount, candCount, refCount;
  __shared__ float sV64;

  const int tid  = threadIdx.x;
  const int wave = tid >> 6, lane = tid & 63;
  const int row  = blockIdx.x;
  const ushort_t* zr = Z + (size_t)row * D_HIDDEN;

  ushort8 u8v[8];
#pragma unroll
  for (int i = 0; i < 8; ++i) u8v[i] = *(const ushort8*)&zr[i * 2048 + tid * 8];
#define ZIDX(i, j) ((i) * 2048 + tid * 8 + (j))

  for (int k = tid; k < 512 * 9; k += 256) hist[k] = 0;
  if (tid == 0) { sTbin = -1; selCount = 0; candCount = 0; refCount = 0; }
  __syncthreads();

  const int cpy = lane & 7;
#pragma unroll
  for (int i = 0; i < 8; ++i)
#pragma unroll
    for (int j = 0; j < 8; ++j) {
      ushort_t w = u8v[i][j];
      if (w) atomicAdd(&hist[((int)(w >> 6)) * 9 + cpy], 1);
    }
  __syncthreads();

  int h0 = 0, h1 = 0;
#pragma unroll
  for (int c = 0; c < 8; ++c) {
    int cc = (tid + c) & 7;
    h0 += hist[(2 * tid) * 9 + cc];
    h1 += hist[(2 * tid + 1) * 9 + cc];
  }
  const int s = h0 + h1;
  int x = s;
#pragma unroll
  for (int off = 1; off < 64; off <<= 1) {
    int y = __shfl_down(x, off, 64);
    if (lane + off < 64) x += y;
  }
  if (lane == 0) wtot[wave] = x;
  __syncthreads();
  int cross = 0;
  if (wave < 3) cross += wtot[3];
  if (wave < 2) cross += wtot[2];
  if (wave < 1) cross += wtot[1];
  const int Sexc = cross + x - s;
  if (Sexc < TOPK && Sexc + h1 >= TOPK) { sTbin = 2 * tid + 1; sAbove = Sexc; }
  const int c0 = Sexc + h1;
  if (c0 < TOPK && c0 + h0 >= TOPK) { sTbin = 2 * tid; sAbove = c0; }
  __syncthreads();
  const int Tbin = sTbin, nAbove = sAbove;

  if (Tbin < 0) {
#pragma unroll
    for (int i = 0; i < 8; ++i)
#pragma unroll
      for (int j = 0; j < 8; ++j) {
        ushort_t w = u8v[i][j];
        if (w) {
          int p = atomicAdd(&selCount, 1);
          if (p < TOPK) { vals[row * 64 + p] = bf2f(w); idxs[row * 64 + p] = ZIDX(i, j); }
        }
      }
    __syncthreads();
    for (int p2 = min(selCount, TOPK) + tid; p2 < TOPK; p2 += 256) {
      vals[row * 64 + p2] = 0.0f; idxs[row * 64 + p2] = 0;
    }
    return;
  }

#pragma unroll
  for (int i = 0; i < 8; ++i)
#pragma unroll
    for (int j = 0; j < 8; ++j) {
      ushort_t w = u8v[i][j];
      if (w && (int)(w >> 6) == Tbin) {
        int c = atomicAdd(&candCount, 1);
        if (c < 512) { cval[c] = bf2f(w); cidx[c] = ZIDX(i, j); }
      }
    }
  __syncthreads();
  {
    const int r  = TOPK - nAbove;
    const int nc = min(candCount, 512);
    for (int j = tid; j < nc; j += 256) {
      float vj = cval[j]; int ij = cidx[j];
      int rank = 0;
      for (int j2 = 0; j2 < nc; ++j2) {
        float v2 = cval[j2];
        rank += (v2 > vj) || (v2 == vj && cidx[j2] < ij);
      }
      if (rank == r - 1) sV64 = vj;
    }
  }
  __syncthreads();
  const float v64 = sV64;

#pragma unroll
  for (int i = 0; i < 8; ++i)
#pragma unroll
    for (int j = 0; j < 8; ++j) {
      ushort_t w = u8v[i][j];
      if (!w) continue;
      float v = bf2f(w);
      if (v > v64 + DELTA) {
        int p = atomicAdd(&selCount, 1);
        vals[row * 64 + p] = v;
        idxs[row * 64 + p] = ZIDX(i, j);
      } else if (v >= v64 - DELTA) {
        int c = atomicAdd(&refCount, 1);
        if (c < RCAP) ridx[c] = ZIDX(i, j);
      }
    }
  __syncthreads();
  const int nS = selCount;
  const int nR = min(refCount, RCAP);
  const int rNeed = TOPK - nS;

  float xr[16];
  {
    const float* xrb = &x32[(size_t)row * D_MODEL + lane * 16];
#pragma unroll
    for (int q = 0; q < 4; ++q)
      *(float4*)&xr[q * 4] = *(const float4*)&xrb[q * 4];
  }
  for (int c = wave; c < nR; c += 4) {
    const int j = ridx[c];
    const float* wr = &WT32[(size_t)j * D_MODEL];
    double p0 = 0.0, p1 = 0.0;
#pragma unroll
    for (int q = 0; q < 2; ++q) {
      const float4 wa = *(const float4*)&wr[lane * 16 + q * 8];
      const float4 wb = *(const float4*)&wr[lane * 16 + q * 8 + 4];
      p0 += (double)xr[q * 8 + 0] * wa.x + (double)xr[q * 8 + 1] * wa.y
          + (double)xr[q * 8 + 2] * wa.z + (double)xr[q * 8 + 3] * wa.w;
      p1 += (double)xr[q * 8 + 4] * wb.x + (double)xr[q * 8 + 5] * wb.y
          + (double)xr[q * 8 + 6] * wb.z + (double)xr[q * 8 + 7] * wb.w;
    }
    double part = p0 + p1;
#pragma unroll
    for (int off = 32; off > 0; off >>= 1) part += __shfl_down(part, off, 64);
    if (lane == 0) {
      double d = part + (double)benc[j];
      rex[c] = d > 0.0 ? d : 0.0;
    }
  }
  __syncthreads();

  for (int c = tid; c < nR; c += 256) {
    double vc = rex[c]; int ic = ridx[c];
    int rank = 0;
    for (int c2 = 0; c2 < nR; ++c2) {
      double v2 = rex[c2];
      rank += (v2 > vc) || (v2 == vc && ridx[c2] < ic);
    }
    if (rank < rNeed) {
      int p = atomicAdd(&selCount, 1);
      vals[row * 64 + p] = (float)vc;
      idxs[row * 64 + p] = ic;
    }
  }
}

// ---------------------------------------------------------------------------
// Kernel 4: y = b_dec + sum_j vals[j]*W_dec[idx[j],:]  (bf16 gathers, fp32 out)
// ---------------------------------------------------------------------------
__global__ __launch_bounds__(256) void decode_kernel(
    const float* __restrict__ vals, const int* __restrict__ idxs,
    const ushort_t* __restrict__ Wdec_bf, const float* __restrict__ bdec,
    float* __restrict__ Y) {
  __shared__ float sv[2][TOPK];
  __shared__ int   si[2][TOPK];
  const int tid = threadIdx.x;
  const int r0  = blockIdx.x * 2;
  if (tid < 128) {
    int rr = tid >> 6, jj = tid & 63;
    sv[rr][jj] = vals[(r0 + rr) * 64 + jj];
    si[rr][jj] = idxs[(r0 + rr) * 64 + jj];
  }
  __syncthreads();
  const int rr  = tid >> 7;
  const int c0  = (tid & 127) * 8;
  const int row = r0 + rr;
  float4 b0 = *(const float4*)&bdec[c0];
  float4 b1 = *(const float4*)&bdec[c0 + 4];
  float a[8] = {b0.x, b0.y, b0.z, b0.w, b1.x, b1.y, b1.z, b1.w};
#pragma unroll 8
  for (int j = 0; j < TOPK; ++j) {
    const float vj = sv[rr][j];
    ushort8 w = *(const ushort8*)&Wdec_bf[(size_t)si[rr][j] * D_MODEL + c0];
#pragma unroll
    for (int u = 0; u < 8; ++u) a[u] += vj * bf2f(w[u]);
  }
  *(float4*)&Y[(size_t)row * D_MODEL + c0]     = (float4){a[0], a[1], a[2], a[3]};
  *(float4*)&Y[(size_t)row * D_MODEL + c0 + 4] = (float4){a[4], a[5], a[6], a[7]};
}

// ---------------------------------------------------------------------------
extern "C" void kernel_launch(void* const* d_in, const int* in_sizes, int n_in,
                              void* d_out, int out_size, void* d_ws, size_t ws_size,
                              hipStream_t stream) {
  const float* x     = (const float*)d_in[0];
  const float* W_enc = (const float*)d_in[1];
  const float* b_enc = (const float*)d_in[2];
  const float* W_dec = (const float*)d_in[3];
  const float* b_dec = (const float*)d_in[4];

  const size_t WT_BYTES   = (size_t)D_HIDDEN * D_MODEL * sizeof(ushort_t); // 32 MB
  const size_t WT32_BYTES = (size_t)D_HIDDEN * D_MODEL * sizeof(float);    // 64 MB
  const size_t XB_BYTES   = (size_t)N_TOKENS * D_MODEL * sizeof(ushort_t); //  8 MB
  const size_t V_BYTES    = (size_t)N_TOKENS * TOPK * sizeof(float);       //  1 MB
  const size_t F_BYTES    = (size_t)N_TOKENS * sizeof(int);                // 16 KB
  const size_t FIXED      = WT_BYTES + WT32_BYTES + XB_BYTES + 2 * V_BYTES
                          + F_BYTES;                                       // ~106 MB

  int chunk_rows = 4096;  // bf16 Z chunk: 128 MB -> total ~234 MB; auto-shrink
  while (chunk_rows > 128 &&
         FIXED + (size_t)chunk_rows * D_HIDDEN * sizeof(ushort_t) > ws_size)
    chunk_rows >>= 1;

  char* ws = (char*)d_ws;
  size_t off = 0;
  ushort_t* WT    = (ushort_t*)(ws + off); off += WT_BYTES;
  float*    WT32  = (float*)(ws + off);    off += WT32_BYTES;
  ushort_t* XB    = (ushort_t*)(ws + off); off += XB_BYTES;
  float*    vals  = (float*)(ws + off);    off += V_BYTES;
  int*      idxs  = (int*)(ws + off);      off += V_BYTES;
  int*      flags = (int*)(ws + off);      off += F_BYTES;
  ushort_t* Z     = (ushort_t*)(ws + off);
  float*    Y     = (float*)d_out;

  cast_x_kernel<<<dim3(N_TOKENS * D_MODEL / 1024), 256, 0, stream>>>(x, XB);
  transpose_cast_kernel<<<dim3(D_HIDDEN / 64, D_MODEL / 64), 256, 0, stream>>>(
      W_enc, WT, WT32);

  for (int r0 = 0; r0 < N_TOKENS; r0 += chunk_rows) {
    encode_gemm<<<dim3(D_HIDDEN / 128, chunk_rows / 128), 256, 0, stream>>>(
        XB + (size_t)r0 * D_MODEL, WT, b_enc, Z);
    topk_fused_kernel<<<dim3(chunk_rows), 256, 0, stream>>>(
        Z, x + (size_t)r0 * D_MODEL, WT32, b_enc,
        vals + (size_t)r0 * TOPK, idxs + (size_t)r0 * TOPK, flags + r0);
    topk_fallback_kernel<<<dim3(chunk_rows), 256, 0, stream>>>(
        flags + r0, Z, x + (size_t)r0 * D_MODEL, WT32, b_enc,
        vals + (size_t)r0 * TOPK, idxs + (size_t)r0 * TOPK);
  }

  cast_wdec_kernel<<<dim3(D_HIDDEN * D_MODEL / (256 * 8)), 256, 0, stream>>>(W_dec, WT);

  decode_kernel<<<dim3(N_TOKENS / 2), 256, 0, stream>>>(vals, idxs, WT, b_dec, Y);
}